// Round 1
// baseline (503.296 us; speedup 1.0000x reference)
//
#include <hip/hip_runtime.h>
#include <math.h>

#define ALPHA 0.5f
#define BETA 0.9f
#define Bsz 512
#define Tsz 512
#define Dsz 256

__device__ __forceinline__ float wave_reduce_sum(float v) {
    // butterfly across 64 lanes; result valid in every lane
    v += __shfl_xor(v, 32, 64);
    v += __shfl_xor(v, 16, 64);
    v += __shfl_xor(v, 8, 64);
    v += __shfl_xor(v, 4, 64);
    v += __shfl_xor(v, 2, 64);
    v += __shfl_xor(v, 1, 64);
    return v;
}

__device__ __forceinline__ float wave_reduce_max(float v) {
    v = fmaxf(v, __shfl_xor(v, 32, 64));
    v = fmaxf(v, __shfl_xor(v, 16, 64));
    v = fmaxf(v, __shfl_xor(v, 8, 64));
    v = fmaxf(v, __shfl_xor(v, 4, 64));
    v = fmaxf(v, __shfl_xor(v, 2, 64));
    v = fmaxf(v, __shfl_xor(v, 1, 64));
    return v;
}

// Kernel A: per batch row b — mean-pooled q, t_max; then Qk = (q @ W_Q.T) @ W_K, scaled 1/sqrt(D)
__global__ __launch_bounds__(256) void kA(const float* __restrict__ x,
                                          const float* __restrict__ ts,
                                          const unsigned char* __restrict__ pad,
                                          const float* __restrict__ WQ,
                                          const float* __restrict__ WK,
                                          float* __restrict__ qk,
                                          float* __restrict__ tmax_out) {
    const int b = blockIdx.x;
    const int tid = threadIdx.x;
    const int w = tid >> 6, lane = tid & 63;

    __shared__ float validS[Tsz];
    __shared__ float qpart[4][Dsz];
    __shared__ float qS[Dsz];
    __shared__ float QS[Dsz];
    __shared__ float red[8];
    __shared__ float tmaxS, cntS;

    // ---- step 1: valid flags, masked t_max, valid count ----
    float lmax = -1e30f;
    float lcnt = 0.f;
    for (int t = tid; t < Tsz; t += 256) {
        bool v = (pad[(size_t)b * Tsz + t] == 0);
        float tv = ts[(size_t)b * Tsz + t];
        validS[t] = v ? 1.f : 0.f;
        if (v) { lmax = fmaxf(lmax, tv); lcnt += 1.f; }
    }
    lmax = wave_reduce_max(lmax);
    lcnt = wave_reduce_sum(lcnt);
    if (lane == 0) { red[w] = lmax; red[4 + w] = lcnt; }
    __syncthreads();
    if (tid == 0) {
        tmaxS = fmaxf(fmaxf(red[0], red[1]), fmaxf(red[2], red[3]));
        cntS = fmaxf(red[4] + red[5] + red[6] + red[7], 1.f);
    }
    __syncthreads();

    // ---- step 2: q = sum_t valid_t * x[b,t,:] / count  (wave w handles t % 4 == w) ----
    const float* xb = x + (size_t)b * Tsz * Dsz;
    float4 accq = make_float4(0.f, 0.f, 0.f, 0.f);
    for (int t = w; t < Tsz; t += 4) {
        float vm = validS[t];
        float4 xv = *(const float4*)(xb + (size_t)t * Dsz + lane * 4);
        accq.x += vm * xv.x; accq.y += vm * xv.y;
        accq.z += vm * xv.z; accq.w += vm * xv.w;
    }
    qpart[w][lane * 4 + 0] = accq.x;
    qpart[w][lane * 4 + 1] = accq.y;
    qpart[w][lane * 4 + 2] = accq.z;
    qpart[w][lane * 4 + 3] = accq.w;
    __syncthreads();
    qS[tid] = (qpart[0][tid] + qpart[1][tid] + qpart[2][tid] + qpart[3][tid]) / cntS;
    __syncthreads();

    // ---- step 3: Q[i] = sum_d q[d] * WQ[i,d] ----
    float Qi = 0.f;
    const float* wqrow = WQ + (size_t)tid * Dsz;
    #pragma unroll 4
    for (int d4 = 0; d4 < Dsz; d4 += 4) {
        float4 wv = *(const float4*)(wqrow + d4);
        Qi += wv.x * qS[d4] + wv.y * qS[d4 + 1] + wv.z * qS[d4 + 2] + wv.w * qS[d4 + 3];
    }
    QS[tid] = Qi;
    __syncthreads();

    // ---- step 4: Qk[d] = sum_e Q[e] * WK[e,d], scaled 1/sqrt(D)=1/16 ----
    float v = 0.f;
    #pragma unroll 8
    for (int e = 0; e < Dsz; ++e) {
        v += QS[e] * WK[(size_t)e * Dsz + tid];
    }
    qk[(size_t)b * Dsz + tid] = v * 0.0625f;
    if (tid == 0) tmax_out[b] = tmaxS;
}

// Kernel B: per batch row b — streaming scores+exp+weighted-sum (softmax denominators cancel),
// then L_t = W_V @ xw, delta, M, T_event, p — all outputs written here.
__global__ __launch_bounds__(256) void kB(const float* __restrict__ x,
                                          const float* __restrict__ ts,
                                          const unsigned char* __restrict__ pad,
                                          const float* __restrict__ qk,
                                          const float* __restrict__ tmax_in,
                                          const float* __restrict__ WV,
                                          const float* __restrict__ prevL,
                                          const float* __restrict__ prevM,
                                          const float* __restrict__ clsw,
                                          const float* __restrict__ clsb,
                                          float* __restrict__ out) {
    const int b = blockIdx.x;
    const int tid = threadIdx.x;
    const int w = tid >> 6, lane = tid & 63;

    __shared__ float lamS[Tsz];
    __shared__ float okS[Tsz];
    __shared__ float accS[4][Dsz];
    __shared__ float EGS[8];
    __shared__ float xwS[Dsz];
    __shared__ float red[4];
    __shared__ float red2[4];

    // ---- decay weights + validity per t ----
    const float tmax = tmax_in[b];
    for (int t = tid; t < Tsz; t += 256) {
        bool valid = (pad[(size_t)b * Tsz + t] == 0);
        float dt = fmaxf(tmax - ts[(size_t)b * Tsz + t], 0.f) * (1.f / 86400.f);
        lamS[t] = valid ? __expf(-ALPHA * dt) : 0.f;
        okS[t] = valid ? 1.f : 0.f;
    }
    __syncthreads();

    // ---- streaming pass: s_t = Qk . x_t (pre-scaled), accumulate E, G, g*x ----
    const float4 qk4 = *(const float4*)(qk + (size_t)b * Dsz + lane * 4);
    const float* xb = x + (size_t)b * Tsz * Dsz;
    float4 acc = make_float4(0.f, 0.f, 0.f, 0.f);
    float E = 0.f, G = 0.f;
    for (int t = w; t < Tsz; t += 4) {
        float4 xv = *(const float4*)(xb + (size_t)t * Dsz + lane * 4);
        float s = qk4.x * xv.x + qk4.y * xv.y + qk4.z * xv.z + qk4.w * xv.w;
        s = wave_reduce_sum(s);               // full dot over D, broadcast to all lanes
        float e = okS[t] * __expf(s);         // masked scores contribute 0 (matches -1e9 -> exp -> 0)
        float g = lamS[t] * e;
        E += e; G += g;
        acc.x += g * xv.x; acc.y += g * xv.y;
        acc.z += g * xv.z; acc.w += g * xv.w;
    }
    accS[w][lane * 4 + 0] = acc.x;
    accS[w][lane * 4 + 1] = acc.y;
    accS[w][lane * 4 + 2] = acc.z;
    accS[w][lane * 4 + 3] = acc.w;
    if (lane == 0) { EGS[w] = E; EGS[4 + w] = G; }
    __syncthreads();

    {
        float Et = EGS[0] + EGS[1] + EGS[2] + EGS[3];
        float Gt = EGS[4] + EGS[5] + EGS[6] + EGS[7];
        float denom = Gt + 1e-8f * Et;        // == (sum lam*attn + 1e-8) up to exact softmax algebra
        float accd = accS[0][tid] + accS[1][tid] + accS[2][tid] + accS[3][tid];
        xwS[tid] = (denom > 0.f) ? accd / denom : 0.f;
    }
    __syncthreads();

    // ---- epilogue: L = W_V @ xw; delta; M; p; writes ----
    float Le = 0.f;
    const float* wvrow = WV + (size_t)tid * Dsz;
    #pragma unroll 4
    for (int d4 = 0; d4 < Dsz; d4 += 4) {
        float4 wv = *(const float4*)(wvrow + d4);
        Le += wv.x * xwS[d4] + wv.y * xwS[d4 + 1] + wv.z * xwS[d4 + 2] + wv.w * xwS[d4 + 3];
    }
    float delta = Le - prevL[(size_t)b * Dsz + tid];

    float ssq = wave_reduce_sum(delta * delta);
    if (lane == 0) red[w] = ssq;
    __syncthreads();
    float nrm = sqrtf(red[0] + red[1] + red[2] + red[3]);
    float M = BETA * prevM[b] + (1.f - BETA) * nrm;

    float pp = Le * clsw[tid] + delta * clsw[Dsz + tid];
    float psum = wave_reduce_sum(pp);
    if (lane == 0) red2[w] = psum;
    __syncthreads();

    float* out_p = out;
    float* out_T = out + Bsz;
    float* out_L = out + Bsz + (size_t)Bsz * (2 * Dsz + 1);
    float* out_M = out + Bsz + (size_t)Bsz * (2 * Dsz + 1) + (size_t)Bsz * Dsz;

    out_T[(size_t)b * (2 * Dsz + 1) + tid] = Le;
    out_T[(size_t)b * (2 * Dsz + 1) + Dsz + tid] = delta;
    out_L[(size_t)b * Dsz + tid] = Le;
    if (tid == 0) {
        float p = red2[0] + red2[1] + red2[2] + red2[3] + M * clsw[2 * Dsz] + clsb[0];
        out_p[b] = p;
        out_T[(size_t)b * (2 * Dsz + 1) + 2 * Dsz] = M;
        out_M[b] = M;
    }
}

extern "C" void kernel_launch(void* const* d_in, const int* in_sizes, int n_in,
                              void* d_out, int out_size, void* d_ws, size_t ws_size,
                              hipStream_t stream) {
    const float* x     = (const float*)d_in[0];
    const float* ts    = (const float*)d_in[1];
    const float* prevL = (const float*)d_in[2];
    const float* prevM = (const float*)d_in[3];
    const unsigned char* pad = (const unsigned char*)d_in[4];
    const float* WQ    = (const float*)d_in[5];
    const float* WK    = (const float*)d_in[6];
    const float* WV    = (const float*)d_in[7];
    const float* clsw  = (const float*)d_in[8];
    const float* clsb  = (const float*)d_in[9];

    float* ws   = (float*)d_ws;
    float* qk   = ws;                 // [B, D]
    float* tmax = ws + Bsz * Dsz;     // [B]

    kA<<<Bsz, 256, 0, stream>>>(x, ts, pad, WQ, WK, qk, tmax);
    kB<<<Bsz, 256, 0, stream>>>(x, ts, pad, qk, tmax, WV, prevL, prevM, clsw, clsb, (float*)d_out);
}

// Round 2
// 453.325 us; speedup vs baseline: 1.1102x; 1.1102x over previous
//
#include <hip/hip_runtime.h>
#include <math.h>

#define ALPHA 0.5f
#define BETA 0.9f
#define Bsz 512
#define Tsz 512
#define Dsz 256

__device__ __forceinline__ float wave_reduce_sum(float v) {
    v += __shfl_xor(v, 32, 64);
    v += __shfl_xor(v, 16, 64);
    v += __shfl_xor(v, 8, 64);
    v += __shfl_xor(v, 4, 64);
    v += __shfl_xor(v, 2, 64);
    v += __shfl_xor(v, 1, 64);
    return v;
}

__device__ __forceinline__ float wave_reduce_max(float v) {
    v = fmaxf(v, __shfl_xor(v, 32, 64));
    v = fmaxf(v, __shfl_xor(v, 16, 64));
    v = fmaxf(v, __shfl_xor(v, 8, 64));
    v = fmaxf(v, __shfl_xor(v, 4, 64));
    v = fmaxf(v, __shfl_xor(v, 2, 64));
    v = fmaxf(v, __shfl_xor(v, 1, 64));
    return v;
}

// Kernel A: per batch row b — mean-pooled q, t_max; then Qk = (q @ W_Q.T) @ W_K, scaled 1/sqrt(D)
__global__ __launch_bounds__(256) void kA(const float* __restrict__ x,
                                          const float* __restrict__ ts,
                                          const unsigned char* __restrict__ pad,
                                          const float* __restrict__ WQ,
                                          const float* __restrict__ WK,
                                          float* __restrict__ qk,
                                          float* __restrict__ tmax_out) {
    const int b = blockIdx.x;
    const int tid = threadIdx.x;
    const int w = tid >> 6, lane = tid & 63;

    __shared__ float validS[Tsz];
    __shared__ float qpart[4][Dsz];
    __shared__ float qS[Dsz];
    __shared__ float QS[Dsz];
    __shared__ float red[8];
    __shared__ float tmaxS, cntS;

    // ---- step 1: valid flags, masked t_max, valid count ----
    float lmax = -1e30f;
    float lcnt = 0.f;
    for (int t = tid; t < Tsz; t += 256) {
        bool v = (pad[(size_t)b * Tsz + t] == 0);
        float tv = ts[(size_t)b * Tsz + t];
        validS[t] = v ? 1.f : 0.f;
        if (v) { lmax = fmaxf(lmax, tv); lcnt += 1.f; }
    }
    lmax = wave_reduce_max(lmax);
    lcnt = wave_reduce_sum(lcnt);
    if (lane == 0) { red[w] = lmax; red[4 + w] = lcnt; }
    __syncthreads();
    if (tid == 0) {
        tmaxS = fmaxf(fmaxf(red[0], red[1]), fmaxf(red[2], red[3]));
        cntS = fmaxf(red[4] + red[5] + red[6] + red[7], 1.f);
    }
    __syncthreads();

    // ---- step 2: q = sum_t valid_t * x[b,t,:] / count ----
    // wave w owns contiguous rows [w*128, w*128+128); 4 rows/iter -> 4 independent
    // load+FMA chains (>=4KB in flight per wave).
    const float* xb = x + (size_t)b * Tsz * Dsz;
    float4 a0 = make_float4(0.f, 0.f, 0.f, 0.f);
    float4 a1 = a0, a2 = a0, a3 = a0;
    const int tbase = w * 128;
    for (int i = 0; i < 128; i += 4) {
        const int t = tbase + i;
        float4 x0 = *(const float4*)(xb + (size_t)(t + 0) * Dsz + lane * 4);
        float4 x1 = *(const float4*)(xb + (size_t)(t + 1) * Dsz + lane * 4);
        float4 x2 = *(const float4*)(xb + (size_t)(t + 2) * Dsz + lane * 4);
        float4 x3 = *(const float4*)(xb + (size_t)(t + 3) * Dsz + lane * 4);
        const float v0 = validS[t], v1 = validS[t + 1], v2 = validS[t + 2], v3 = validS[t + 3];
        a0.x += v0 * x0.x; a0.y += v0 * x0.y; a0.z += v0 * x0.z; a0.w += v0 * x0.w;
        a1.x += v1 * x1.x; a1.y += v1 * x1.y; a1.z += v1 * x1.z; a1.w += v1 * x1.w;
        a2.x += v2 * x2.x; a2.y += v2 * x2.y; a2.z += v2 * x2.z; a2.w += v2 * x2.w;
        a3.x += v3 * x3.x; a3.y += v3 * x3.y; a3.z += v3 * x3.z; a3.w += v3 * x3.w;
    }
    float4 accq;
    accq.x = (a0.x + a1.x) + (a2.x + a3.x);
    accq.y = (a0.y + a1.y) + (a2.y + a3.y);
    accq.z = (a0.z + a1.z) + (a2.z + a3.z);
    accq.w = (a0.w + a1.w) + (a2.w + a3.w);
    qpart[w][lane * 4 + 0] = accq.x;
    qpart[w][lane * 4 + 1] = accq.y;
    qpart[w][lane * 4 + 2] = accq.z;
    qpart[w][lane * 4 + 3] = accq.w;
    __syncthreads();
    qS[tid] = (qpart[0][tid] + qpart[1][tid] + qpart[2][tid] + qpart[3][tid]) / cntS;
    __syncthreads();

    // ---- step 3: Q[i] = sum_d q[d] * WQ[i,d] ----
    float Qi = 0.f;
    const float* wqrow = WQ + (size_t)tid * Dsz;
    #pragma unroll 4
    for (int d4 = 0; d4 < Dsz; d4 += 4) {
        float4 wv = *(const float4*)(wqrow + d4);
        Qi += wv.x * qS[d4] + wv.y * qS[d4 + 1] + wv.z * qS[d4 + 2] + wv.w * qS[d4 + 3];
    }
    QS[tid] = Qi;
    __syncthreads();

    // ---- step 4: Qk[d] = sum_e Q[e] * WK[e,d], scaled 1/sqrt(D)=1/16 ----
    float v = 0.f;
    #pragma unroll 8
    for (int e = 0; e < Dsz; ++e) {
        v += QS[e] * WK[(size_t)e * Dsz + tid];
    }
    qk[(size_t)b * Dsz + tid] = v * 0.0625f;
    if (tid == 0) tmax_out[b] = tmaxS;
}

// Kernel B: per batch row b — streaming scores+exp+weighted-sum (softmax denominators cancel),
// then L_t = W_V @ xw, delta, M, T_event, p.
__global__ __launch_bounds__(256) void kB(const float* __restrict__ x,
                                          const float* __restrict__ ts,
                                          const unsigned char* __restrict__ pad,
                                          const float* __restrict__ qk,
                                          const float* __restrict__ tmax_in,
                                          const float* __restrict__ WV,
                                          const float* __restrict__ prevL,
                                          const float* __restrict__ prevM,
                                          const float* __restrict__ clsw,
                                          const float* __restrict__ clsb,
                                          float* __restrict__ out) {
    const int b = blockIdx.x;
    const int tid = threadIdx.x;
    const int w = tid >> 6, lane = tid & 63;

    __shared__ float lamS[Tsz];
    __shared__ float okS[Tsz];
    __shared__ float accS[4][Dsz];
    __shared__ float EGS[8];
    __shared__ float xwS[Dsz];
    __shared__ float red[4];
    __shared__ float red2[4];

    // ---- decay weights + validity per t ----
    const float tmax = tmax_in[b];
    for (int t = tid; t < Tsz; t += 256) {
        bool valid = (pad[(size_t)b * Tsz + t] == 0);
        float dt = fmaxf(tmax - ts[(size_t)b * Tsz + t], 0.f) * (1.f / 86400.f);
        lamS[t] = valid ? __expf(-ALPHA * dt) : 0.f;
        okS[t] = valid ? 1.f : 0.f;
    }
    __syncthreads();

    // ---- streaming pass: 4 rows/iter, interleaved butterfly (ILP=4 on the shfl chain) ----
    const float4 qk4 = *(const float4*)(qk + (size_t)b * Dsz + lane * 4);
    const float* xb = x + (size_t)b * Tsz * Dsz;
    float4 acc = make_float4(0.f, 0.f, 0.f, 0.f);
    float E = 0.f, G = 0.f;
    const int tbase = w * 128;
    for (int i = 0; i < 128; i += 4) {
        const int t = tbase + i;
        float4 x0 = *(const float4*)(xb + (size_t)(t + 0) * Dsz + lane * 4);
        float4 x1 = *(const float4*)(xb + (size_t)(t + 1) * Dsz + lane * 4);
        float4 x2 = *(const float4*)(xb + (size_t)(t + 2) * Dsz + lane * 4);
        float4 x3 = *(const float4*)(xb + (size_t)(t + 3) * Dsz + lane * 4);
        float s0 = qk4.x * x0.x + qk4.y * x0.y + qk4.z * x0.z + qk4.w * x0.w;
        float s1 = qk4.x * x1.x + qk4.y * x1.y + qk4.z * x1.z + qk4.w * x1.w;
        float s2 = qk4.x * x2.x + qk4.y * x2.y + qk4.z * x2.z + qk4.w * x2.w;
        float s3 = qk4.x * x3.x + qk4.y * x3.y + qk4.z * x3.z + qk4.w * x3.w;
        #pragma unroll
        for (int off = 32; off >= 1; off >>= 1) {
            s0 += __shfl_xor(s0, off, 64);
            s1 += __shfl_xor(s1, off, 64);
            s2 += __shfl_xor(s2, off, 64);
            s3 += __shfl_xor(s3, off, 64);
        }
        float e0 = okS[t + 0] * __expf(s0);
        float e1 = okS[t + 1] * __expf(s1);
        float e2 = okS[t + 2] * __expf(s2);
        float e3 = okS[t + 3] * __expf(s3);
        float g0 = lamS[t + 0] * e0;
        float g1 = lamS[t + 1] * e1;
        float g2 = lamS[t + 2] * e2;
        float g3 = lamS[t + 3] * e3;
        E += (e0 + e1) + (e2 + e3);
        G += (g0 + g1) + (g2 + g3);
        acc.x += g0 * x0.x + g1 * x1.x + g2 * x2.x + g3 * x3.x;
        acc.y += g0 * x0.y + g1 * x1.y + g2 * x2.y + g3 * x3.y;
        acc.z += g0 * x0.z + g1 * x1.z + g2 * x2.z + g3 * x3.z;
        acc.w += g0 * x0.w + g1 * x1.w + g2 * x2.w + g3 * x3.w;
    }
    accS[w][lane * 4 + 0] = acc.x;
    accS[w][lane * 4 + 1] = acc.y;
    accS[w][lane * 4 + 2] = acc.z;
    accS[w][lane * 4 + 3] = acc.w;
    if (lane == 0) { EGS[w] = E; EGS[4 + w] = G; }
    __syncthreads();

    {
        float Et = EGS[0] + EGS[1] + EGS[2] + EGS[3];
        float Gt = EGS[4] + EGS[5] + EGS[6] + EGS[7];
        float denom = Gt + 1e-8f * Et;  // == (sum lam*attn + 1e-8) up to exact softmax algebra
        float accd = accS[0][tid] + accS[1][tid] + accS[2][tid] + accS[3][tid];
        xwS[tid] = (denom > 0.f) ? accd / denom : 0.f;
    }
    __syncthreads();

    // ---- epilogue: L = W_V @ xw; delta; M; p; writes ----
    float Le = 0.f;
    const float* wvrow = WV + (size_t)tid * Dsz;
    #pragma unroll 4
    for (int d4 = 0; d4 < Dsz; d4 += 4) {
        float4 wv = *(const float4*)(wvrow + d4);
        Le += wv.x * xwS[d4] + wv.y * xwS[d4 + 1] + wv.z * xwS[d4 + 2] + wv.w * xwS[d4 + 3];
    }
    float delta = Le - prevL[(size_t)b * Dsz + tid];

    float ssq = wave_reduce_sum(delta * delta);
    if (lane == 0) red[w] = ssq;
    __syncthreads();
    float nrm = sqrtf(red[0] + red[1] + red[2] + red[3]);
    float M = BETA * prevM[b] + (1.f - BETA) * nrm;

    float pp = Le * clsw[tid] + delta * clsw[Dsz + tid];
    float psum = wave_reduce_sum(pp);
    if (lane == 0) red2[w] = psum;
    __syncthreads();

    float* out_p = out;
    float* out_T = out + Bsz;
    float* out_L = out + Bsz + (size_t)Bsz * (2 * Dsz + 1);
    float* out_M = out + Bsz + (size_t)Bsz * (2 * Dsz + 1) + (size_t)Bsz * Dsz;

    out_T[(size_t)b * (2 * Dsz + 1) + tid] = Le;
    out_T[(size_t)b * (2 * Dsz + 1) + Dsz + tid] = delta;
    out_L[(size_t)b * Dsz + tid] = Le;
    if (tid == 0) {
        float p = red2[0] + red2[1] + red2[2] + red2[3] + M * clsw[2 * Dsz] + clsb[0];
        out_p[b] = p;
        out_T[(size_t)b * (2 * Dsz + 1) + 2 * Dsz] = M;
        out_M[b] = M;
    }
}

extern "C" void kernel_launch(void* const* d_in, const int* in_sizes, int n_in,
                              void* d_out, int out_size, void* d_ws, size_t ws_size,
                              hipStream_t stream) {
    const float* x     = (const float*)d_in[0];
    const float* ts    = (const float*)d_in[1];
    const float* prevL = (const float*)d_in[2];
    const float* prevM = (const float*)d_in[3];
    const unsigned char* pad = (const unsigned char*)d_in[4];
    const float* WQ    = (const float*)d_in[5];
    const float* WK    = (const float*)d_in[6];
    const float* WV    = (const float*)d_in[7];
    const float* clsw  = (const float*)d_in[8];
    const float* clsb  = (const float*)d_in[9];

    float* ws   = (float*)d_ws;
    float* qk   = ws;                 // [B, D]
    float* tmax = ws + Bsz * Dsz;     // [B]

    kA<<<Bsz, 256, 0, stream>>>(x, ts, pad, WQ, WK, qk, tmax);
    kB<<<Bsz, 256, 0, stream>>>(x, ts, pad, qk, tmax, WV, prevL, prevM, clsw, clsb, (float*)d_out);
}